// Round 1
// baseline (1334.148 us; speedup 1.0000x reference)
//
#include <hip/hip_runtime.h>
#include <stdint.h>

#define NTHR 256
#define PP   64      // patches per block
#define KPOS 81      // 9x9 spatial positions per conv1 channel
#define HL_S 72      // H LDS stride (pad 64 -> 72 so k*144 bytes is 16B aligned)
#define W2_S 132     // W2 LDS stride (pad 128 -> 132 to break write bank conflicts)

__device__ __forceinline__ float bf_lo(uint32_t u){ return __uint_as_float(u << 16); }
__device__ __forceinline__ float bf_hi(uint32_t u){ return __uint_as_float(u & 0xffff0000u); }
// float -> bf16 bits, round-to-nearest-even
__device__ __forceinline__ uint16_t f2bf(float f){
    uint32_t x = __float_as_uint(f);
    uint32_t r = (x + 0x7fffu + ((x >> 16) & 1u)) >> 16;
    return (uint16_t)r;
}
__device__ __forceinline__ float bfu2f(uint16_t u){ return __uint_as_float(((uint32_t)u) << 16); }

__global__ __launch_bounds__(NTHR, 2)
void patch_embed(const float* __restrict__ images,
                 const float* __restrict__ coords,
                 const int*   __restrict__ t_src,
                 const float* __restrict__ W1,
                 const float* __restrict__ b1,
                 const float* __restrict__ W2,
                 const float* __restrict__ b2,
                 float* __restrict__ out)
{
    // LDS: 31104 + 11664 + 21384 + 256 = 64408 B  (<= 64 KB, 2 blocks/CU)
    __shared__ __align__(16) uint16_t patches[PP*243];   // [p][c*81 + y*9 + x], bf16
    __shared__ __align__(16) uint16_t Hl[KPOS*HL_S];     // [k][p], bf16
    __shared__ __align__(16) uint16_t W2l[KPOS*W2_S];    // [k][oc], bf16
    __shared__ int poff[PP];

    const int tid = threadIdx.x;
    const int blk = blockIdx.x;
    const int HW  = 384*384;

    // ---- per-patch source offsets (round-half-even like jnp.round) ----
    if (tid < PP) {
        int gp = blk*PP + tid;
        int b = gp >> 11;          // / 2048
        int n = gp & 2047;
        float cx = coords[(size_t)(b*2048 + n)*2 + 0];
        float cy = coords[(size_t)(b*2048 + n)*2 + 1];
        int u = (int)rintf(cx * 384.0f);
        int v = (int)rintf(cy * 384.0f);
        u = min(max(u, 4), 379);
        v = min(max(v, 4), 379);
        int t = t_src[b*2048 + n];
        t = min(max(t, 0), 15);
        poff[tid] = ((b*16 + t)*3)*HW + (v-4)*384 + (u-4);
    }
    __syncthreads();

    // ---- stage 64 patches (3x9x9 each) into LDS as bf16 ----
    for (int i = tid; i < PP*243; i += NTHR) {
        int p  = i / 243;
        int r  = i - p*243;
        int c  = r / 81;
        int yx = r - c*81;
        int y  = yx / 9;
        int x  = yx - y*9;
        patches[i] = f2bf(images[(size_t)poff[p] + c*HW + y*384 + x]);
    }

    // conv2 accumulators: 8 patches x 4 output channels per thread
    const int pg  = tid & 7;
    const int og  = tid >> 3;
    const int p0  = pg * 8;
    const int oc0 = og * 4;

    float acc[8][4];
    #pragma unroll
    for (int i = 0; i < 8; ++i) {
        #pragma unroll
        for (int j = 0; j < 4; ++j) acc[i][j] = 0.0f;
    }

    __syncthreads();

    // ---- K loop: one conv1 output channel (81 k-values) per chunk ----
    for (int c1 = 0; c1 < 64; ++c1) {
        // stage W2[:, c1, :, :] -> W2l[yx][oc] (transposed, bf16)
        const float* w2s = W2 + c1*KPOS;
        for (int i = tid; i < 128*KPOS; i += NTHR) {
            int oc = i / KPOS;
            int yx = i - oc*KPOS;
            W2l[yx*W2_S + oc] = f2bf(w2s[(size_t)oc*(64*KPOS) + yx]);
        }

        // conv1 weights for this channel (uniform -> scalar loads)
        float w1r[27];
        #pragma unroll
        for (int j = 0; j < 27; ++j) w1r[j] = W1[c1*27 + j];
        const float bias1 = b1[c1];

        // conv1: each task = one output row (9 outputs) of one patch
        for (int t = tid; t < PP*9; t += NTHR) {
            const int p  = t & (PP-1);
            const int yo = t >> 6;
            float a[9];
            #pragma unroll
            for (int x = 0; x < 9; ++x) a[x] = bias1;
            #pragma unroll
            for (int c = 0; c < 3; ++c) {
                #pragma unroll
                for (int dy = 0; dy < 3; ++dy) {
                    const int yy = yo - 1 + dy;
                    if (yy >= 0 && yy <= 8) {
                        const uint16_t* prow = patches + p*243 + c*81 + yy*9;
                        float r[9];
                        #pragma unroll
                        for (int x = 0; x < 9; ++x) r[x] = bfu2f(prow[x]);
                        const float wa = w1r[c*9 + dy*3 + 0];
                        const float wb = w1r[c*9 + dy*3 + 1];
                        const float wc = w1r[c*9 + dy*3 + 2];
                        #pragma unroll
                        for (int xo = 0; xo < 9; ++xo) {
                            if (xo >= 1) a[xo] = fmaf(r[xo-1], wa, a[xo]);
                            a[xo] = fmaf(r[xo], wb, a[xo]);
                            if (xo <= 7) a[xo] = fmaf(r[xo+1], wc, a[xo]);
                        }
                    }
                }
            }
            #pragma unroll
            for (int xo = 0; xo < 9; ++xo) {
                float v = a[xo] > 0.0f ? a[xo] : 0.0f;   // ReLU
                Hl[(yo*9 + xo)*HL_S + p] = f2bf(v);
            }
        }

        __syncthreads();   // Hl and W2l ready

        // conv2 partial GEMM: acc[p][oc] += H[p][k] * W2[oc][k]
        #pragma unroll 3
        for (int k = 0; k < KPOS; ++k) {
            const uint4 hv = *reinterpret_cast<const uint4*>(Hl  + k*HL_S + p0);   // 8 bf16 (16B aligned)
            const uint2 wv = *reinterpret_cast<const uint2*>(W2l + k*W2_S + oc0);  // 4 bf16 (8B aligned)
            float hf[8], wf[4];
            hf[0]=bf_lo(hv.x); hf[1]=bf_hi(hv.x);
            hf[2]=bf_lo(hv.y); hf[3]=bf_hi(hv.y);
            hf[4]=bf_lo(hv.z); hf[5]=bf_hi(hv.z);
            hf[6]=bf_lo(hv.w); hf[7]=bf_hi(hv.w);
            wf[0]=bf_lo(wv.x); wf[1]=bf_hi(wv.x);
            wf[2]=bf_lo(wv.y); wf[3]=bf_hi(wv.y);
            #pragma unroll
            for (int i = 0; i < 8; ++i) {
                #pragma unroll
                for (int j = 0; j < 4; ++j)
                    acc[i][j] = fmaf(hf[i], wf[j], acc[i][j]);
            }
        }

        __syncthreads();   // before overwriting Hl/W2l next chunk
    }

    // ---- epilogue: add b2, write (B,N,128) fp32 ----
    const float4 b2v = *reinterpret_cast<const float4*>(b2 + oc0);
    #pragma unroll
    for (int i = 0; i < 8; ++i) {
        int gp = blk*PP + p0 + i;
        float4 o;
        o.x = acc[i][0] + b2v.x;
        o.y = acc[i][1] + b2v.y;
        o.z = acc[i][2] + b2v.z;
        o.w = acc[i][3] + b2v.w;
        *reinterpret_cast<float4*>(out + (size_t)gp*128 + oc0) = o;
    }
}

extern "C" void kernel_launch(void* const* d_in, const int* in_sizes, int n_in,
                              void* d_out, int out_size, void* d_ws, size_t ws_size,
                              hipStream_t stream)
{
    const float* images = (const float*)d_in[0];
    const float* coords = (const float*)d_in[1];
    const int*   t_src  = (const int*)d_in[2];
    const float* W1     = (const float*)d_in[3];
    const float* b1     = (const float*)d_in[4];
    const float* W2     = (const float*)d_in[5];
    const float* b2     = (const float*)d_in[6];
    float* out = (float*)d_out;

    dim3 grid(512), block(NTHR);
    hipLaunchKernelGGL(patch_embed, grid, block, 0, stream,
                       images, coords, t_src, W1, b1, W2, b2, out);
}